// Round 4
// baseline (174.150 us; speedup 1.0000x reference)
//
#include <hip/hip_runtime.h>

// TemplatePointwiseAttention on MI355X (gfx950).
// T=4 templates, R=384, d_t=64, d_z=128, H=4 heads, D=16.
// All GEMMs transposed (C = W^T * X^T), pixels on the MFMA column axis.
// R3: fix R2's q_kernel LDS under-allocation (8KB declared, 16KB written ->
// garbage Q). Q exchange now uses a fragment-native layout so pass A stores
// and pass B loads are fully coalesced. Both passes: 768 blocks x 4 waves x
// exactly 3 tiles (perfect balance), 3 blocks/CU resident.

typedef __bf16 bf16x8 __attribute__((ext_vector_type(8)));
typedef float f32x4 __attribute__((ext_vector_type(4)));
typedef unsigned int u32x4 __attribute__((ext_vector_type(4)));
typedef unsigned int u32x2 __attribute__((ext_vector_type(2)));

#define MFMA16(A, B, C) __builtin_amdgcn_mfma_f32_16x16x32_bf16((A), (B), (C), 0, 0, 0)

__device__ __forceinline__ unsigned int f2b_pk(float a, float b) {
  unsigned int ua = __float_as_uint(a), ub = __float_as_uint(b);
  ua = (ua + 0x7fffu + ((ua >> 16) & 1u)) >> 16;
  ub = (ub + 0x7fffu + ((ub >> 16) & 1u)) & 0xffff0000u;
  return ua | ub;
}

__device__ __forceinline__ bf16x8 pack8(float4 a, float4 b) {
  u32x4 u;
  u.x = f2b_pk(a.x, a.y);
  u.y = f2b_pk(a.z, a.w);
  u.z = f2b_pk(b.x, b.y);
  u.w = f2b_pk(b.z, b.w);
  return __builtin_bit_cast(bf16x8, u);
}

__device__ __forceinline__ bf16x8 ldg8(const float* p) {
  const float4* q = (const float4*)p;
  return pack8(q[0], q[1]);
}

// A-fragment from XOR-swizzled LDS image: row-major [M][K] bf16,
// swizzle byte ^= (row&7)<<4 (kills bank conflicts on 128/256B strides)
__device__ __forceinline__ bf16x8 ldsA(const char* smem, int baseByte, int row,
                                       int colElem, int strideElem) {
  int off = baseByte + (((row * strideElem + colElem) * 2) ^ ((row & 7) << 4));
  return __builtin_bit_cast(bf16x8, *(const u32x4*)(smem + off));
}

__device__ __forceinline__ void stage_w(char* smem, int off, float v, int r, int j) {
  unsigned int u = __float_as_uint(v);
  *(unsigned short*)(smem + off + ((j * 2) ^ ((r & 7) << 4))) =
      (unsigned short)((u + 0x7fffu + ((u >> 16) & 1u)) >> 16);
}

// ---------------- Pass A: Q^T = (wq^T * 0.25) * z^T, bf16 out ----------------
// LDS: [0,16384) wq^T [64][128] bf16 (16 KB — R2 under-allocated this!)
// Q exchange layout: q_[(tile*4 + h)*64 + lane] as u32x2 (fragment-native,
// coalesced on both sides).
__global__ __launch_bounds__(256, 4)
void q_kernel(const float* __restrict__ z_, const float* __restrict__ wq_,
              u32x2* __restrict__ q_) {
  extern __shared__ char smem[];
  for (int i = threadIdx.x; i < 8192; i += 256) {
    int r = i >> 7, cc = i & 127;
    stage_w(smem, 0, wq_[cc * 64 + r] * 0.25f, r, i);
  }
  __syncthreads();
  const int lane = threadIdx.x & 63;
  const int wid = threadIdx.x >> 6;
  const int c = lane & 15, g = lane >> 4;
  const f32x4 vz = {0.f, 0.f, 0.f, 0.f};
  // 768 blocks x 4 waves x 3 tiles = 9216 exactly
  for (int tile = blockIdx.x * 4 + wid; tile < 9216; tile += 3072) {
    const int p = tile * 16 + c;
    const float* zp = z_ + (size_t)p * 128;
    f32x4 qacc[4] = {vz, vz, vz, vz};
#pragma unroll
    for (int s = 0; s < 4; ++s) {
      bf16x8 zb = ldg8(zp + s * 32 + g * 8);
#pragma unroll
      for (int h = 0; h < 4; ++h)
        qacc[h] = MFMA16(ldsA(smem, 0, h * 16 + c, s * 32 + g * 8, 128), zb, qacc[h]);
    }
#pragma unroll
    for (int h = 0; h < 4; ++h) {
      u32x2 w;
      w.x = f2b_pk(qacc[h][0], qacc[h][1]);
      w.y = f2b_pk(qacc[h][2], qacc[h][3]);
      q_[(size_t)(tile * 4 + h) * 64 + lane] = w;  // coalesced 512B/wave
    }
  }
}

// ---------------- Pass B: attention + output projection ----------------
// LDS: [0,8192) wk^T [64][64] | [8192,16384) wv^T | [16384,32768) wo^T [128][64]
//      [32768,40960) per-wave O bufs, 4 x [16][64] bf16
__global__ __launch_bounds__(256, 4)
void tpa_b_kernel(const float* __restrict__ t_, const u32x2* __restrict__ q_,
                  const float* __restrict__ mask_,
                  const float* __restrict__ wk_, const float* __restrict__ wv_,
                  const float* __restrict__ wo_, const float* __restrict__ bo_,
                  float* __restrict__ out_) {
  extern __shared__ char smem[];
  for (int i = threadIdx.x; i < 16384; i += 256) {
    if (i < 4096) {
      int r = i >> 6, cc = i & 63;
      stage_w(smem, 0, wk_[cc * 64 + r], r, i);
    } else if (i < 8192) {
      int j = i - 4096, r = j >> 6, cc = j & 63;
      stage_w(smem, 8192, wv_[cc * 64 + r], r, j);
    } else {
      int j = i - 8192, r = j >> 6, cc = j & 63;
      stage_w(smem, 16384, wo_[cc * 128 + r], r, j);
    }
  }
  __syncthreads();

  const int lane = threadIdx.x & 63;
  const int wid = threadIdx.x >> 6;
  const int c = lane & 15, g = lane >> 4;

  const float b0 = mask_[0] > 0.f ? 0.f : -1e9f;
  const float b1 = mask_[1] > 0.f ? 0.f : -1e9f;
  const float b2 = mask_[2] > 0.f ? 0.f : -1e9f;
  const float b3 = mask_[3] > 0.f ? 0.f : -1e9f;

  char* Olds = smem + 32768 + wid * 2048;
  const f32x4 vz = {0.f, 0.f, 0.f, 0.f};

  // 768 blocks x 4 waves x 3 tiles = 9216 exactly
  for (int tile = blockIdx.x * 4 + wid; tile < 9216; tile += 3072) {
    const int p = tile * 16 + c;
    const float* tp = t_ + (size_t)p * 64;

    // ---- load Q fragments (bf16, precomputed; coalesced 512B/wave) ----
    f32x4 qacc[4];
#pragma unroll
    for (int h = 0; h < 4; ++h) {
      u32x2 w = q_[(size_t)(tile * 4 + h) * 64 + lane];
      qacc[h][0] = __uint_as_float(w.x << 16);
      qacc[h][1] = __uint_as_float(w.x & 0xffff0000u);
      qacc[h][2] = __uint_as_float(w.y << 16);
      qacc[h][3] = __uint_as_float(w.y & 0xffff0000u);
    }

    // ---- per-template: K,V share t fragments; un-shifted softmax ----
    f32x4 oacc[4] = {vz, vz, vz, vz};
    float ssum[4] = {0.f, 0.f, 0.f, 0.f};
#pragma unroll
    for (int tt = 0; tt < 4; ++tt) {
      const float* tq = tp + (size_t)tt * 9437184;  // tt * R*R*64
      bf16x8 tb0 = ldg8(tq + g * 8);
      bf16x8 tb1 = ldg8(tq + 32 + g * 8);
      f32x4 kacc[4], vacc[4];
#pragma unroll
      for (int h = 0; h < 4; ++h) {
        kacc[h] = MFMA16(ldsA(smem, 0, h * 16 + c, g * 8, 64), tb0, vz);
        kacc[h] = MFMA16(ldsA(smem, 0, h * 16 + c, 32 + g * 8, 64), tb1, kacc[h]);
        vacc[h] = MFMA16(ldsA(smem, 8192, h * 16 + c, g * 8, 64), tb0, vz);
        vacc[h] = MFMA16(ldsA(smem, 8192, h * 16 + c, 32 + g * 8, 64), tb1, vacc[h]);
      }
      const float bt = (tt == 0) ? b0 : (tt == 1) ? b1 : (tt == 2) ? b2 : b3;
#pragma unroll
      for (int h = 0; h < 4; ++h) {
        float d = qacc[h][0] * kacc[h][0] + qacc[h][1] * kacc[h][1] +
                  qacc[h][2] * kacc[h][2] + qacc[h][3] * kacc[h][3];
        d += __shfl_xor(d, 16);
        d += __shfl_xor(d, 32);  // full dot broadcast to all 4 g-groups
        float e = __expf(d + bt);
        ssum[h] += e;
        oacc[h] += e * vacc[h];
      }
    }

    // ---- normalize, O -> LDS as bf16 (swizzled) ----
#pragma unroll
    for (int h = 0; h < 4; ++h) {
      float inv = 1.0f / ssum[h];
      f32x4 o = oacc[h] * inv;
      u32x2 w;
      w.x = f2b_pk(o[0], o[1]);
      w.y = f2b_pk(o[2], o[3]);
      int off = (c * 128 + h * 32 + g * 8) ^ ((c & 7) << 4);
      *(u32x2*)(Olds + off) = w;
    }
    asm volatile("s_waitcnt lgkmcnt(0)" ::: "memory");  // intra-wave LDS exchange

    // ---- OUT^T = wo^T (A, LDS) * O^T (B, LDS): 2 K-steps x 8 M-tiles ----
    f32x4 outacc[8] = {vz, vz, vz, vz, vz, vz, vz, vz};
#pragma unroll
    for (int s = 0; s < 2; ++s) {
      int off = (c * 128 + s * 64 + g * 16) ^ ((c & 7) << 4);
      bf16x8 ob = __builtin_bit_cast(bf16x8, *(const u32x4*)(Olds + off));
#pragma unroll
      for (int m = 0; m < 8; ++m)
        outacc[m] = MFMA16(ldsA(smem, 16384, m * 16 + c, s * 32 + g * 8, 64), ob, outacc[m]);
    }

    // ---- +bo, store ----
    float* op = out_ + (size_t)p * 128;
    const float4* bop = (const float4*)bo_;
#pragma unroll
    for (int m = 0; m < 8; ++m) {
      float4 bv = bop[m * 4 + g];
      float4 st;
      st.x = outacc[m][0] + bv.x;
      st.y = outacc[m][1] + bv.y;
      st.z = outacc[m][2] + bv.z;
      st.w = outacc[m][3] + bv.w;
      *(float4*)(op + m * 16 + g * 4) = st;
    }
    asm volatile("" ::: "memory");
  }
}

// ---------------- Fallback: R0 single-pass (verified), if ws too small ------
__global__ __launch_bounds__(256, 2)
void tpa_fused(const float* __restrict__ t_, const float* __restrict__ z_,
               const float* __restrict__ mask_,
               const float* __restrict__ wq_, const float* __restrict__ wk_,
               const float* __restrict__ wv_, const float* __restrict__ wo_,
               const float* __restrict__ bo_, float* __restrict__ out_) {
  extern __shared__ char smem[];
  for (int i = threadIdx.x; i < 24576; i += 256) {
    if (i < 8192) {
      int r = i >> 7;
      stage_w(smem, 0, wq_[(i & 127) * 64 + r] * 0.25f, r, i);
    } else if (i < 12288) {
      int j = i - 8192, r = j >> 6;
      stage_w(smem, 16384, wk_[(j & 63) * 64 + r], r, j);
    } else if (i < 16384) {
      int j = i - 12288, r = j >> 6;
      stage_w(smem, 24576, wv_[(j & 63) * 64 + r], r, j);
    } else {
      int j = i - 16384, r = j >> 6;
      stage_w(smem, 32768, wo_[(j & 63) * 128 + r], r, j);
    }
  }
  __syncthreads();
  const int lane = threadIdx.x & 63;
  const int wid = threadIdx.x >> 6;
  const int c = lane & 15, g = lane >> 4;
  const float b0 = mask_[0] > 0.f ? 0.f : -1e9f;
  const float b1 = mask_[1] > 0.f ? 0.f : -1e9f;
  const float b2 = mask_[2] > 0.f ? 0.f : -1e9f;
  const float b3 = mask_[3] > 0.f ? 0.f : -1e9f;
  char* Olds = smem + 49152 + wid * 2048;
  const f32x4 vz = {0.f, 0.f, 0.f, 0.f};
  for (int tile = blockIdx.x * 4 + wid; tile < 9216; tile += 2048) {
    const int p = tile * 16 + c;
    const float* zp = z_ + (size_t)p * 128;
    const float* tp = t_ + (size_t)p * 64;
    f32x4 qacc[4] = {vz, vz, vz, vz};
#pragma unroll
    for (int s = 0; s < 4; ++s) {
      bf16x8 zb = ldg8(zp + s * 32 + g * 8);
#pragma unroll
      for (int h = 0; h < 4; ++h)
        qacc[h] = MFMA16(ldsA(smem, 0, h * 16 + c, s * 32 + g * 8, 128), zb, qacc[h]);
    }
    f32x4 oacc[4] = {vz, vz, vz, vz};
    float ssum[4] = {0.f, 0.f, 0.f, 0.f};
#pragma unroll
    for (int tt = 0; tt < 4; ++tt) {
      const float* tq = tp + (size_t)tt * 9437184;
      bf16x8 tb0 = ldg8(tq + g * 8);
      bf16x8 tb1 = ldg8(tq + 32 + g * 8);
      f32x4 kacc[4], vacc[4];
#pragma unroll
      for (int h = 0; h < 4; ++h) {
        kacc[h] = MFMA16(ldsA(smem, 16384, h * 16 + c, g * 8, 64), tb0, vz);
        kacc[h] = MFMA16(ldsA(smem, 16384, h * 16 + c, 32 + g * 8, 64), tb1, kacc[h]);
        vacc[h] = MFMA16(ldsA(smem, 24576, h * 16 + c, g * 8, 64), tb0, vz);
        vacc[h] = MFMA16(ldsA(smem, 24576, h * 16 + c, 32 + g * 8, 64), tb1, vacc[h]);
      }
      const float bt = (tt == 0) ? b0 : (tt == 1) ? b1 : (tt == 2) ? b2 : b3;
#pragma unroll
      for (int h = 0; h < 4; ++h) {
        float d = qacc[h][0] * kacc[h][0] + qacc[h][1] * kacc[h][1] +
                  qacc[h][2] * kacc[h][2] + qacc[h][3] * kacc[h][3];
        d += __shfl_xor(d, 16);
        d += __shfl_xor(d, 32);
        float e = __expf(d + bt);
        ssum[h] += e;
        oacc[h] += e * vacc[h];
      }
    }
#pragma unroll
    for (int h = 0; h < 4; ++h) {
      float inv = 1.0f / ssum[h];
      f32x4 o = oacc[h] * inv;
      u32x2 w;
      w.x = f2b_pk(o[0], o[1]);
      w.y = f2b_pk(o[2], o[3]);
      int off = (c * 128 + h * 32 + g * 8) ^ ((c & 7) << 4);
      *(u32x2*)(Olds + off) = w;
    }
    asm volatile("s_waitcnt lgkmcnt(0)" ::: "memory");
    f32x4 outacc[8] = {vz, vz, vz, vz, vz, vz, vz, vz};
#pragma unroll
    for (int s = 0; s < 2; ++s) {
      int off = (c * 128 + s * 64 + g * 16) ^ ((c & 7) << 4);
      bf16x8 ob = __builtin_bit_cast(bf16x8, *(const u32x4*)(Olds + off));
#pragma unroll
      for (int m = 0; m < 8; ++m)
        outacc[m] = MFMA16(ldsA(smem, 32768, m * 16 + c, s * 32 + g * 8, 64), ob, outacc[m]);
    }
    float* op = out_ + (size_t)p * 128;
    const float4* bop = (const float4*)bo_;
#pragma unroll
    for (int m = 0; m < 8; ++m) {
      float4 bv = bop[m * 4 + g];
      float4 st;
      st.x = outacc[m][0] + bv.x;
      st.y = outacc[m][1] + bv.y;
      st.z = outacc[m][2] + bv.z;
      st.w = outacc[m][3] + bv.w;
      *(float4*)(op + m * 16 + g * 4) = st;
    }
    asm volatile("" ::: "memory");
  }
}

extern "C" void kernel_launch(void* const* d_in, const int* in_sizes, int n_in,
                              void* d_out, int out_size, void* d_ws, size_t ws_size,
                              hipStream_t stream) {
  const float* t = (const float*)d_in[0];
  const float* z = (const float*)d_in[1];
  const float* mk = (const float*)d_in[2];
  const float* wq = (const float*)d_in[3];
  const float* wk = (const float*)d_in[4];
  const float* wv = (const float*)d_in[5];
  const float* wo = (const float*)d_in[6];
  const float* bo = (const float*)d_in[7];
  float* out = (float*)d_out;
  (void)in_sizes; (void)n_in; (void)out_size;

  const size_t qbytes = (size_t)9216 * 4 * 64 * 8;  // Q fragments as u32x2
  if (ws_size >= qbytes) {
    u32x2* qws = (u32x2*)d_ws;
    hipLaunchKernelGGL(q_kernel, dim3(768), dim3(256), 16384, stream, z, wq, qws);
    hipLaunchKernelGGL(tpa_b_kernel, dim3(768), dim3(256), 40960, stream,
                       t, qws, mk, wk, wv, wo, bo, out);
  } else {
    hipLaunchKernelGGL(tpa_fused, dim3(512), dim3(256), 57344, stream,
                       t, z, mk, wq, wk, wv, wo, bo, out);
  }
}

// Round 5
// 122.818 us; speedup vs baseline: 1.4180x; 1.4180x over previous
//
#include <hip/hip_runtime.h>

// TemplatePointwiseAttention on MI355X (gfx950).
// T=4 templates, R=384, d_t=64, d_z=128, H=4 heads, D=16.
// All GEMMs transposed (C = W^T * X^T), pixels on the MFMA column axis.
// R4: identical structure to R3; ONLY change is __launch_bounds__(256,2)
// (R1/R4 showed min-waves=4 makes the allocator clamp to 64 VGPR and spill
// ~170MB of scratch writes; R0's (256,2) gave 120 VGPR, zero spill) and
// grid residency (pass B 1024 blocks = 4 blocks/CU at 40KB LDS).

typedef __bf16 bf16x8 __attribute__((ext_vector_type(8)));
typedef float f32x4 __attribute__((ext_vector_type(4)));
typedef unsigned int u32x4 __attribute__((ext_vector_type(4)));
typedef unsigned int u32x2 __attribute__((ext_vector_type(2)));

#define MFMA16(A, B, C) __builtin_amdgcn_mfma_f32_16x16x32_bf16((A), (B), (C), 0, 0, 0)

__device__ __forceinline__ unsigned int f2b_pk(float a, float b) {
  unsigned int ua = __float_as_uint(a), ub = __float_as_uint(b);
  ua = (ua + 0x7fffu + ((ua >> 16) & 1u)) >> 16;
  ub = (ub + 0x7fffu + ((ub >> 16) & 1u)) & 0xffff0000u;
  return ua | ub;
}

__device__ __forceinline__ bf16x8 pack8(float4 a, float4 b) {
  u32x4 u;
  u.x = f2b_pk(a.x, a.y);
  u.y = f2b_pk(a.z, a.w);
  u.z = f2b_pk(b.x, b.y);
  u.w = f2b_pk(b.z, b.w);
  return __builtin_bit_cast(bf16x8, u);
}

__device__ __forceinline__ bf16x8 ldg8(const float* p) {
  const float4* q = (const float4*)p;
  return pack8(q[0], q[1]);
}

// A-fragment from XOR-swizzled LDS image: row-major [M][K] bf16,
// swizzle byte ^= (row&7)<<4 (kills bank conflicts on 128/256B strides)
__device__ __forceinline__ bf16x8 ldsA(const char* smem, int baseByte, int row,
                                       int colElem, int strideElem) {
  int off = baseByte + (((row * strideElem + colElem) * 2) ^ ((row & 7) << 4));
  return __builtin_bit_cast(bf16x8, *(const u32x4*)(smem + off));
}

__device__ __forceinline__ void stage_w(char* smem, int off, float v, int r, int j) {
  unsigned int u = __float_as_uint(v);
  *(unsigned short*)(smem + off + ((j * 2) ^ ((r & 7) << 4))) =
      (unsigned short)((u + 0x7fffu + ((u >> 16) & 1u)) >> 16);
}

// ---------------- Pass A: Q^T = (wq^T * 0.25) * z^T, bf16 out ----------------
// LDS: [0,16384) wq^T [64][128] bf16.
// Q exchange layout: q_[(tile*4 + h)*64 + lane] as u32x2 (fragment-native,
// coalesced both sides).
__global__ __launch_bounds__(256, 2)
void q_kernel(const float* __restrict__ z_, const float* __restrict__ wq_,
              u32x2* __restrict__ q_) {
  extern __shared__ char smem[];
  for (int i = threadIdx.x; i < 8192; i += 256) {
    int r = i >> 7, cc = i & 127;
    stage_w(smem, 0, wq_[cc * 64 + r] * 0.25f, r, i);
  }
  __syncthreads();
  const int lane = threadIdx.x & 63;
  const int wid = threadIdx.x >> 6;
  const int c = lane & 15, g = lane >> 4;
  const f32x4 vz = {0.f, 0.f, 0.f, 0.f};
  // 1152 blocks x 4 waves x 2 tiles = 9216 exactly
  for (int tile = blockIdx.x * 4 + wid; tile < 9216; tile += 4608) {
    const int p = tile * 16 + c;
    const float* zp = z_ + (size_t)p * 128;
    f32x4 qacc[4] = {vz, vz, vz, vz};
#pragma unroll
    for (int s = 0; s < 4; ++s) {
      bf16x8 zb = ldg8(zp + s * 32 + g * 8);
#pragma unroll
      for (int h = 0; h < 4; ++h)
        qacc[h] = MFMA16(ldsA(smem, 0, h * 16 + c, s * 32 + g * 8, 128), zb, qacc[h]);
    }
#pragma unroll
    for (int h = 0; h < 4; ++h) {
      u32x2 w;
      w.x = f2b_pk(qacc[h][0], qacc[h][1]);
      w.y = f2b_pk(qacc[h][2], qacc[h][3]);
      q_[(size_t)(tile * 4 + h) * 64 + lane] = w;  // coalesced 512B/wave
    }
  }
}

// ---------------- Pass B: attention + output projection ----------------
// LDS: [0,8192) wk^T [64][64] | [8192,16384) wv^T | [16384,32768) wo^T [128][64]
//      [32768,40960) per-wave O bufs, 4 x [16][64] bf16
__global__ __launch_bounds__(256, 2)
void tpa_b_kernel(const float* __restrict__ t_, const u32x2* __restrict__ q_,
                  const float* __restrict__ mask_,
                  const float* __restrict__ wk_, const float* __restrict__ wv_,
                  const float* __restrict__ wo_, const float* __restrict__ bo_,
                  float* __restrict__ out_) {
  extern __shared__ char smem[];
  for (int i = threadIdx.x; i < 16384; i += 256) {
    if (i < 4096) {
      int r = i >> 6, cc = i & 63;
      stage_w(smem, 0, wk_[cc * 64 + r], r, i);
    } else if (i < 8192) {
      int j = i - 4096, r = j >> 6, cc = j & 63;
      stage_w(smem, 8192, wv_[cc * 64 + r], r, j);
    } else {
      int j = i - 8192, r = j >> 6, cc = j & 63;
      stage_w(smem, 16384, wo_[cc * 128 + r], r, j);
    }
  }
  __syncthreads();

  const int lane = threadIdx.x & 63;
  const int wid = threadIdx.x >> 6;
  const int c = lane & 15, g = lane >> 4;

  const float b0 = mask_[0] > 0.f ? 0.f : -1e9f;
  const float b1 = mask_[1] > 0.f ? 0.f : -1e9f;
  const float b2 = mask_[2] > 0.f ? 0.f : -1e9f;
  const float b3 = mask_[3] > 0.f ? 0.f : -1e9f;

  char* Olds = smem + 32768 + wid * 2048;
  const f32x4 vz = {0.f, 0.f, 0.f, 0.f};

  // 1024 blocks x 4 waves, grid-stride (2-3 tiles/wave); 4 blocks/CU resident
  for (int tile = blockIdx.x * 4 + wid; tile < 9216; tile += 4096) {
    const int p = tile * 16 + c;
    const float* tp = t_ + (size_t)p * 64;

    // ---- load Q fragments (bf16, precomputed; coalesced 512B/wave) ----
    f32x4 qacc[4];
#pragma unroll
    for (int h = 0; h < 4; ++h) {
      u32x2 w = q_[(size_t)(tile * 4 + h) * 64 + lane];
      qacc[h][0] = __uint_as_float(w.x << 16);
      qacc[h][1] = __uint_as_float(w.x & 0xffff0000u);
      qacc[h][2] = __uint_as_float(w.y << 16);
      qacc[h][3] = __uint_as_float(w.y & 0xffff0000u);
    }

    // ---- per-template: K,V share t fragments; un-shifted softmax ----
    f32x4 oacc[4] = {vz, vz, vz, vz};
    float ssum[4] = {0.f, 0.f, 0.f, 0.f};
#pragma unroll
    for (int tt = 0; tt < 4; ++tt) {
      const float* tq = tp + (size_t)tt * 9437184;  // tt * R*R*64
      bf16x8 tb0 = ldg8(tq + g * 8);
      bf16x8 tb1 = ldg8(tq + 32 + g * 8);
      f32x4 kacc[4], vacc[4];
#pragma unroll
      for (int h = 0; h < 4; ++h) {
        kacc[h] = MFMA16(ldsA(smem, 0, h * 16 + c, g * 8, 64), tb0, vz);
        kacc[h] = MFMA16(ldsA(smem, 0, h * 16 + c, 32 + g * 8, 64), tb1, kacc[h]);
        vacc[h] = MFMA16(ldsA(smem, 8192, h * 16 + c, g * 8, 64), tb0, vz);
        vacc[h] = MFMA16(ldsA(smem, 8192, h * 16 + c, 32 + g * 8, 64), tb1, vacc[h]);
      }
      const float bt = (tt == 0) ? b0 : (tt == 1) ? b1 : (tt == 2) ? b2 : b3;
#pragma unroll
      for (int h = 0; h < 4; ++h) {
        float d = qacc[h][0] * kacc[h][0] + qacc[h][1] * kacc[h][1] +
                  qacc[h][2] * kacc[h][2] + qacc[h][3] * kacc[h][3];
        d += __shfl_xor(d, 16);
        d += __shfl_xor(d, 32);  // full dot broadcast to all 4 g-groups
        float e = __expf(d + bt);
        ssum[h] += e;
        oacc[h] += e * vacc[h];
      }
    }

    // ---- normalize, O -> LDS as bf16 (swizzled) ----
#pragma unroll
    for (int h = 0; h < 4; ++h) {
      float inv = 1.0f / ssum[h];
      f32x4 o = oacc[h] * inv;
      u32x2 w;
      w.x = f2b_pk(o[0], o[1]);
      w.y = f2b_pk(o[2], o[3]);
      int off = (c * 128 + h * 32 + g * 8) ^ ((c & 7) << 4);
      *(u32x2*)(Olds + off) = w;
    }
    asm volatile("s_waitcnt lgkmcnt(0)" ::: "memory");  // intra-wave LDS exchange

    // ---- OUT^T = wo^T (A, LDS) * O^T (B, LDS): 2 K-steps x 8 M-tiles ----
    f32x4 outacc[8] = {vz, vz, vz, vz, vz, vz, vz, vz};
#pragma unroll
    for (int s = 0; s < 2; ++s) {
      int off = (c * 128 + s * 64 + g * 16) ^ ((c & 7) << 4);
      bf16x8 ob = __builtin_bit_cast(bf16x8, *(const u32x4*)(Olds + off));
#pragma unroll
      for (int m = 0; m < 8; ++m)
        outacc[m] = MFMA16(ldsA(smem, 16384, m * 16 + c, s * 32 + g * 8, 64), ob, outacc[m]);
    }

    // ---- +bo, store ----
    float* op = out_ + (size_t)p * 128;
    const float4* bop = (const float4*)bo_;
#pragma unroll
    for (int m = 0; m < 8; ++m) {
      float4 bv = bop[m * 4 + g];
      float4 st;
      st.x = outacc[m][0] + bv.x;
      st.y = outacc[m][1] + bv.y;
      st.z = outacc[m][2] + bv.z;
      st.w = outacc[m][3] + bv.w;
      *(float4*)(op + m * 16 + g * 4) = st;
    }
    asm volatile("" ::: "memory");
  }
}

// ---------------- Fallback: R0 single-pass (verified), if ws too small ------
__global__ __launch_bounds__(256, 2)
void tpa_fused(const float* __restrict__ t_, const float* __restrict__ z_,
               const float* __restrict__ mask_,
               const float* __restrict__ wq_, const float* __restrict__ wk_,
               const float* __restrict__ wv_, const float* __restrict__ wo_,
               const float* __restrict__ bo_, float* __restrict__ out_) {
  extern __shared__ char smem[];
  for (int i = threadIdx.x; i < 24576; i += 256) {
    if (i < 8192) {
      int r = i >> 7;
      stage_w(smem, 0, wq_[(i & 127) * 64 + r] * 0.25f, r, i);
    } else if (i < 12288) {
      int j = i - 8192, r = j >> 6;
      stage_w(smem, 16384, wk_[(j & 63) * 64 + r], r, j);
    } else if (i < 16384) {
      int j = i - 12288, r = j >> 6;
      stage_w(smem, 24576, wv_[(j & 63) * 64 + r], r, j);
    } else {
      int j = i - 16384, r = j >> 6;
      stage_w(smem, 32768, wo_[(j & 63) * 128 + r], r, j);
    }
  }
  __syncthreads();
  const int lane = threadIdx.x & 63;
  const int wid = threadIdx.x >> 6;
  const int c = lane & 15, g = lane >> 4;
  const float b0 = mask_[0] > 0.f ? 0.f : -1e9f;
  const float b1 = mask_[1] > 0.f ? 0.f : -1e9f;
  const float b2 = mask_[2] > 0.f ? 0.f : -1e9f;
  const float b3 = mask_[3] > 0.f ? 0.f : -1e9f;
  char* Olds = smem + 49152 + wid * 2048;
  const f32x4 vz = {0.f, 0.f, 0.f, 0.f};
  for (int tile = blockIdx.x * 4 + wid; tile < 9216; tile += 2048) {
    const int p = tile * 16 + c;
    const float* zp = z_ + (size_t)p * 128;
    const float* tp = t_ + (size_t)p * 64;
    f32x4 qacc[4] = {vz, vz, vz, vz};
#pragma unroll
    for (int s = 0; s < 4; ++s) {
      bf16x8 zb = ldg8(zp + s * 32 + g * 8);
#pragma unroll
      for (int h = 0; h < 4; ++h)
        qacc[h] = MFMA16(ldsA(smem, 0, h * 16 + c, s * 32 + g * 8, 128), zb, qacc[h]);
    }
    f32x4 oacc[4] = {vz, vz, vz, vz};
    float ssum[4] = {0.f, 0.f, 0.f, 0.f};
#pragma unroll
    for (int tt = 0; tt < 4; ++tt) {
      const float* tq = tp + (size_t)tt * 9437184;
      bf16x8 tb0 = ldg8(tq + g * 8);
      bf16x8 tb1 = ldg8(tq + 32 + g * 8);
      f32x4 kacc[4], vacc[4];
#pragma unroll
      for (int h = 0; h < 4; ++h) {
        kacc[h] = MFMA16(ldsA(smem, 16384, h * 16 + c, g * 8, 64), tb0, vz);
        kacc[h] = MFMA16(ldsA(smem, 16384, h * 16 + c, 32 + g * 8, 64), tb1, kacc[h]);
        vacc[h] = MFMA16(ldsA(smem, 24576, h * 16 + c, g * 8, 64), tb0, vz);
        vacc[h] = MFMA16(ldsA(smem, 24576, h * 16 + c, 32 + g * 8, 64), tb1, vacc[h]);
      }
      const float bt = (tt == 0) ? b0 : (tt == 1) ? b1 : (tt == 2) ? b2 : b3;
#pragma unroll
      for (int h = 0; h < 4; ++h) {
        float d = qacc[h][0] * kacc[h][0] + qacc[h][1] * kacc[h][1] +
                  qacc[h][2] * kacc[h][2] + qacc[h][3] * kacc[h][3];
        d += __shfl_xor(d, 16);
        d += __shfl_xor(d, 32);
        float e = __expf(d + bt);
        ssum[h] += e;
        oacc[h] += e * vacc[h];
      }
    }
#pragma unroll
    for (int h = 0; h < 4; ++h) {
      float inv = 1.0f / ssum[h];
      f32x4 o = oacc[h] * inv;
      u32x2 w;
      w.x = f2b_pk(o[0], o[1]);
      w.y = f2b_pk(o[2], o[3]);
      int off = (c * 128 + h * 32 + g * 8) ^ ((c & 7) << 4);
      *(u32x2*)(Olds + off) = w;
    }
    asm volatile("s_waitcnt lgkmcnt(0)" ::: "memory");
    f32x4 outacc[8] = {vz, vz, vz, vz, vz, vz, vz, vz};
#pragma unroll
    for (int s = 0; s < 2; ++s) {
      int off = (c * 128 + s * 64 + g * 16) ^ ((c & 7) << 4);
      bf16x8 ob = __builtin_bit_cast(bf16x8, *(const u32x4*)(Olds + off));
#pragma unroll
      for (int m = 0; m < 8; ++m)
        outacc[m] = MFMA16(ldsA(smem, 32768, m * 16 + c, s * 32 + g * 8, 64), ob, outacc[m]);
    }
    float* op = out_ + (size_t)p * 128;
    const float4* bop = (const float4*)bo_;
#pragma unroll
    for (int m = 0; m < 8; ++m) {
      float4 bv = bop[m * 4 + g];
      float4 st;
      st.x = outacc[m][0] + bv.x;
      st.y = outacc[m][1] + bv.y;
      st.z = outacc[m][2] + bv.z;
      st.w = outacc[m][3] + bv.w;
      *(float4*)(op + m * 16 + g * 4) = st;
    }
    asm volatile("" ::: "memory");
  }
}

extern "C" void kernel_launch(void* const* d_in, const int* in_sizes, int n_in,
                              void* d_out, int out_size, void* d_ws, size_t ws_size,
                              hipStream_t stream) {
  const float* t = (const float*)d_in[0];
  const float* z = (const float*)d_in[1];
  const float* mk = (const float*)d_in[2];
  const float* wq = (const float*)d_in[3];
  const float* wk = (const float*)d_in[4];
  const float* wv = (const float*)d_in[5];
  const float* wo = (const float*)d_in[6];
  const float* bo = (const float*)d_in[7];
  float* out = (float*)d_out;
  (void)in_sizes; (void)n_in; (void)out_size;

  const size_t qbytes = (size_t)9216 * 4 * 64 * 8;  // Q fragments as u32x2
  if (ws_size >= qbytes) {
    u32x2* qws = (u32x2*)d_ws;
    hipLaunchKernelGGL(q_kernel, dim3(1152), dim3(256), 16384, stream, z, wq, qws);
    hipLaunchKernelGGL(tpa_b_kernel, dim3(1024), dim3(256), 40960, stream,
                       t, qws, mk, wk, wv, wo, bo, out);
  } else {
    hipLaunchKernelGGL(tpa_fused, dim3(512), dim3(256), 57344, stream,
                       t, z, mk, wq, wk, wv, wo, bo, out);
  }
}

// Round 6
// 117.981 us; speedup vs baseline: 1.4761x; 1.0410x over previous
//
#include <hip/hip_runtime.h>

// TemplatePointwiseAttention on MI355X (gfx950).
// T=4 templates, R=384, d_t=64, d_z=128, H=4 heads, D=16.
// All GEMMs transposed (C = W^T * X^T), pixels on the MFMA column axis.
// R6: same two-pass structure/grids as R5. Two changes only:
//  (1) per-tile memory-level parallelism: ALL raw t loads (16 x float4) are
//      issued before any pack/MFMA consumer -> ~1 HBM latency per tile
//      instead of ~16 serialized (R5: 0.7 GB/s per wave-slot, latency-bound).
//  (2) v_cvt_pk_bf16_f32 (1 VALU op per bf16 pair, RNE) replaces the 5-op
//      manual RNE pack in all hot paths (VALU floor ~26us -> ~15us).

typedef __bf16 bf16x8 __attribute__((ext_vector_type(8)));
typedef float f32x4 __attribute__((ext_vector_type(4)));
typedef unsigned int u32x4 __attribute__((ext_vector_type(4)));
typedef unsigned int u32x2 __attribute__((ext_vector_type(2)));

#define MFMA16(A, B, C) __builtin_amdgcn_mfma_f32_16x16x32_bf16((A), (B), (C), 0, 0, 0)

// hardware packed f32->bf16 (RNE): lo -> low16, hi -> high16
__device__ __forceinline__ unsigned int cvtpk(float lo, float hi) {
  unsigned int r;
  asm("v_cvt_pk_bf16_f32 %0, %1, %2" : "=v"(r) : "v"(lo), "v"(hi));
  return r;
}

__device__ __forceinline__ bf16x8 pack8(float4 a, float4 b) {
  u32x4 u;
  u.x = cvtpk(a.x, a.y);
  u.y = cvtpk(a.z, a.w);
  u.z = cvtpk(b.x, b.y);
  u.w = cvtpk(b.z, b.w);
  return __builtin_bit_cast(bf16x8, u);
}

// A-fragment from XOR-swizzled LDS image: row-major [M][K] bf16,
// swizzle byte ^= (row&7)<<4 (kills bank conflicts on 128/256B strides)
__device__ __forceinline__ bf16x8 ldsA(const char* smem, int baseByte, int row,
                                       int colElem, int strideElem) {
  int off = baseByte + (((row * strideElem + colElem) * 2) ^ ((row & 7) << 4));
  return __builtin_bit_cast(bf16x8, *(const u32x4*)(smem + off));
}

__device__ __forceinline__ void stage_w(char* smem, int off, float v, int r, int j) {
  unsigned int u = __float_as_uint(v);
  *(unsigned short*)(smem + off + ((j * 2) ^ ((r & 7) << 4))) =
      (unsigned short)((u + 0x7fffu + ((u >> 16) & 1u)) >> 16);
}

// ---------------- Pass A: Q^T = (wq^T * 0.25) * z^T, bf16 out ----------------
// LDS: [0,16384) wq^T [64][128] bf16.
// Q exchange: q_[(tile*4 + h)*64 + lane] as u32x2 (fragment-native, coalesced).
__global__ __launch_bounds__(256, 2)
void q_kernel(const float* __restrict__ z_, const float* __restrict__ wq_,
              u32x2* __restrict__ q_) {
  extern __shared__ char smem[];
  for (int i = threadIdx.x; i < 8192; i += 256) {
    int r = i >> 7, cc = i & 127;
    stage_w(smem, 0, wq_[cc * 64 + r] * 0.25f, r, i);
  }
  __syncthreads();
  const int lane = threadIdx.x & 63;
  const int wid = threadIdx.x >> 6;
  const int c = lane & 15, g = lane >> 4;
  const f32x4 vz = {0.f, 0.f, 0.f, 0.f};
  // 1152 blocks x 4 waves x 2 tiles = 9216 exactly
  for (int tile = blockIdx.x * 4 + wid; tile < 9216; tile += 4608) {
    const int p = tile * 16 + c;
    const float4* zp = (const float4*)(z_ + (size_t)p * 128 + g * 8);
    // ---- issue all 8 z loads before any consumer ----
    float4 zraw[8];
#pragma unroll
    for (int s = 0; s < 4; ++s) {
      zraw[2 * s]     = zp[s * 8];
      zraw[2 * s + 1] = zp[s * 8 + 1];
    }
    f32x4 qacc[4] = {vz, vz, vz, vz};
#pragma unroll
    for (int s = 0; s < 4; ++s) {
      bf16x8 zb = pack8(zraw[2 * s], zraw[2 * s + 1]);
#pragma unroll
      for (int h = 0; h < 4; ++h)
        qacc[h] = MFMA16(ldsA(smem, 0, h * 16 + c, s * 32 + g * 8, 128), zb, qacc[h]);
    }
#pragma unroll
    for (int h = 0; h < 4; ++h) {
      u32x2 w;
      w.x = cvtpk(qacc[h][0], qacc[h][1]);
      w.y = cvtpk(qacc[h][2], qacc[h][3]);
      q_[(size_t)(tile * 4 + h) * 64 + lane] = w;  // coalesced 512B/wave
    }
  }
}

// ---------------- Pass B: attention + output projection ----------------
// LDS: [0,8192) wk^T [64][64] | [8192,16384) wv^T | [16384,32768) wo^T [128][64]
//      [32768,40960) per-wave O bufs, 4 x [16][64] bf16
__global__ __launch_bounds__(256, 2)
void tpa_b_kernel(const float* __restrict__ t_, const u32x2* __restrict__ q_,
                  const float* __restrict__ mask_,
                  const float* __restrict__ wk_, const float* __restrict__ wv_,
                  const float* __restrict__ wo_, const float* __restrict__ bo_,
                  float* __restrict__ out_) {
  extern __shared__ char smem[];
  for (int i = threadIdx.x; i < 16384; i += 256) {
    if (i < 4096) {
      int r = i >> 6, cc = i & 63;
      stage_w(smem, 0, wk_[cc * 64 + r], r, i);
    } else if (i < 8192) {
      int j = i - 4096, r = j >> 6, cc = j & 63;
      stage_w(smem, 8192, wv_[cc * 64 + r], r, j);
    } else {
      int j = i - 8192, r = j >> 6, cc = j & 63;
      stage_w(smem, 16384, wo_[cc * 128 + r], r, j);
    }
  }
  __syncthreads();

  const int lane = threadIdx.x & 63;
  const int wid = threadIdx.x >> 6;
  const int c = lane & 15, g = lane >> 4;

  const float b0 = mask_[0] > 0.f ? 0.f : -1e9f;
  const float b1 = mask_[1] > 0.f ? 0.f : -1e9f;
  const float b2 = mask_[2] > 0.f ? 0.f : -1e9f;
  const float b3 = mask_[3] > 0.f ? 0.f : -1e9f;

  char* Olds = smem + 32768 + wid * 2048;
  const f32x4 vz = {0.f, 0.f, 0.f, 0.f};

  // 1024 blocks x 4 waves, grid-stride (2-3 tiles/wave)
  for (int tile = blockIdx.x * 4 + wid; tile < 9216; tile += 4096) {
    const int p = tile * 16 + c;
    const float* tp = t_ + (size_t)p * 64 + g * 8;

    // ---- issue ALL 16 raw t loads up front (one latency per tile, not 16) --
    float4 traw[16];
#pragma unroll
    for (int tt = 0; tt < 4; ++tt) {
      const float* tq = tp + (size_t)tt * 9437184;  // tt * R*R*64
      traw[tt * 4 + 0] = *(const float4*)(tq);
      traw[tt * 4 + 1] = *(const float4*)(tq + 4);
      traw[tt * 4 + 2] = *(const float4*)(tq + 32);
      traw[tt * 4 + 3] = *(const float4*)(tq + 36);
    }

    // ---- load Q fragments (bf16, precomputed, L3-warm; coalesced) ----
    f32x4 qacc[4];
#pragma unroll
    for (int h = 0; h < 4; ++h) {
      u32x2 w = q_[(size_t)(tile * 4 + h) * 64 + lane];
      qacc[h][0] = __uint_as_float(w.x << 16);
      qacc[h][1] = __uint_as_float(w.x & 0xffff0000u);
      qacc[h][2] = __uint_as_float(w.y << 16);
      qacc[h][3] = __uint_as_float(w.y & 0xffff0000u);
    }

    // ---- per-template: K,V share t fragments; un-shifted softmax ----
    f32x4 oacc[4] = {vz, vz, vz, vz};
    float ssum[4] = {0.f, 0.f, 0.f, 0.f};
#pragma unroll
    for (int tt = 0; tt < 4; ++tt) {
      bf16x8 tb0 = pack8(traw[tt * 4 + 0], traw[tt * 4 + 1]);
      bf16x8 tb1 = pack8(traw[tt * 4 + 2], traw[tt * 4 + 3]);
      f32x4 kacc[4], vacc[4];
#pragma unroll
      for (int h = 0; h < 4; ++h) {
        kacc[h] = MFMA16(ldsA(smem, 0, h * 16 + c, g * 8, 64), tb0, vz);
        kacc[h] = MFMA16(ldsA(smem, 0, h * 16 + c, 32 + g * 8, 64), tb1, kacc[h]);
        vacc[h] = MFMA16(ldsA(smem, 8192, h * 16 + c, g * 8, 64), tb0, vz);
        vacc[h] = MFMA16(ldsA(smem, 8192, h * 16 + c, 32 + g * 8, 64), tb1, vacc[h]);
      }
      const float bt = (tt == 0) ? b0 : (tt == 1) ? b1 : (tt == 2) ? b2 : b3;
#pragma unroll
      for (int h = 0; h < 4; ++h) {
        float d = qacc[h][0] * kacc[h][0] + qacc[h][1] * kacc[h][1] +
                  qacc[h][2] * kacc[h][2] + qacc[h][3] * kacc[h][3];
        d += __shfl_xor(d, 16);
        d += __shfl_xor(d, 32);  // full dot broadcast to all 4 g-groups
        float e = __expf(d + bt);
        ssum[h] += e;
        oacc[h] += e * vacc[h];
      }
    }

    // ---- normalize, O -> LDS as bf16 (swizzled) ----
#pragma unroll
    for (int h = 0; h < 4; ++h) {
      float inv = 1.0f / ssum[h];
      f32x4 o = oacc[h] * inv;
      u32x2 w;
      w.x = cvtpk(o[0], o[1]);
      w.y = cvtpk(o[2], o[3]);
      int off = (c * 128 + h * 32 + g * 8) ^ ((c & 7) << 4);
      *(u32x2*)(Olds + off) = w;
    }
    asm volatile("s_waitcnt lgkmcnt(0)" ::: "memory");  // intra-wave LDS exchange

    // ---- OUT^T = wo^T (A, LDS) * O^T (B, LDS): 2 K-steps x 8 M-tiles ----
    f32x4 outacc[8] = {vz, vz, vz, vz, vz, vz, vz, vz};
#pragma unroll
    for (int s = 0; s < 2; ++s) {
      int off = (c * 128 + s * 64 + g * 16) ^ ((c & 7) << 4);
      bf16x8 ob = __builtin_bit_cast(bf16x8, *(const u32x4*)(Olds + off));
#pragma unroll
      for (int m = 0; m < 8; ++m)
        outacc[m] = MFMA16(ldsA(smem, 16384, m * 16 + c, s * 32 + g * 8, 64), ob, outacc[m]);
    }

    // ---- +bo, store ----
    float* op = out_ + (size_t)p * 128;
    const float4* bop = (const float4*)bo_;
#pragma unroll
    for (int m = 0; m < 8; ++m) {
      float4 bv = bop[m * 4 + g];
      float4 st;
      st.x = outacc[m][0] + bv.x;
      st.y = outacc[m][1] + bv.y;
      st.z = outacc[m][2] + bv.z;
      st.w = outacc[m][3] + bv.w;
      *(float4*)(op + m * 16 + g * 4) = st;
    }
    asm volatile("" ::: "memory");
  }
}

// ---------------- Fallback: single-pass (verified R0 shape), ws too small ---
__global__ __launch_bounds__(256, 2)
void tpa_fused(const float* __restrict__ t_, const float* __restrict__ z_,
               const float* __restrict__ mask_,
               const float* __restrict__ wq_, const float* __restrict__ wk_,
               const float* __restrict__ wv_, const float* __restrict__ wo_,
               const float* __restrict__ bo_, float* __restrict__ out_) {
  extern __shared__ char smem[];
  for (int i = threadIdx.x; i < 24576; i += 256) {
    if (i < 8192) {
      int r = i >> 7;
      stage_w(smem, 0, wq_[(i & 127) * 64 + r] * 0.25f, r, i);
    } else if (i < 12288) {
      int j = i - 8192, r = j >> 6;
      stage_w(smem, 16384, wk_[(j & 63) * 64 + r], r, j);
    } else if (i < 16384) {
      int j = i - 12288, r = j >> 6;
      stage_w(smem, 24576, wv_[(j & 63) * 64 + r], r, j);
    } else {
      int j = i - 16384, r = j >> 6;
      stage_w(smem, 32768, wo_[(j & 63) * 128 + r], r, j);
    }
  }
  __syncthreads();
  const int lane = threadIdx.x & 63;
  const int wid = threadIdx.x >> 6;
  const int c = lane & 15, g = lane >> 4;
  const float b0 = mask_[0] > 0.f ? 0.f : -1e9f;
  const float b1 = mask_[1] > 0.f ? 0.f : -1e9f;
  const float b2 = mask_[2] > 0.f ? 0.f : -1e9f;
  const float b3 = mask_[3] > 0.f ? 0.f : -1e9f;
  char* Olds = smem + 49152 + wid * 2048;
  const f32x4 vz = {0.f, 0.f, 0.f, 0.f};
  for (int tile = blockIdx.x * 4 + wid; tile < 9216; tile += 2048) {
    const int p = tile * 16 + c;
    const float4* zp = (const float4*)(z_ + (size_t)p * 128 + g * 8);
    const float* tp = t_ + (size_t)p * 64 + g * 8;
    f32x4 qacc[4] = {vz, vz, vz, vz};
#pragma unroll
    for (int s = 0; s < 4; ++s) {
      bf16x8 zb = pack8(zp[s * 8], zp[s * 8 + 1]);
#pragma unroll
      for (int h = 0; h < 4; ++h)
        qacc[h] = MFMA16(ldsA(smem, 0, h * 16 + c, s * 32 + g * 8, 128), zb, qacc[h]);
    }
    f32x4 oacc[4] = {vz, vz, vz, vz};
    float ssum[4] = {0.f, 0.f, 0.f, 0.f};
#pragma unroll
    for (int tt = 0; tt < 4; ++tt) {
      const float* tq = tp + (size_t)tt * 9437184;
      bf16x8 tb0 = pack8(*(const float4*)(tq), *(const float4*)(tq + 4));
      bf16x8 tb1 = pack8(*(const float4*)(tq + 32), *(const float4*)(tq + 36));
      f32x4 kacc[4], vacc[4];
#pragma unroll
      for (int h = 0; h < 4; ++h) {
        kacc[h] = MFMA16(ldsA(smem, 16384, h * 16 + c, g * 8, 64), tb0, vz);
        kacc[h] = MFMA16(ldsA(smem, 16384, h * 16 + c, 32 + g * 8, 64), tb1, kacc[h]);
        vacc[h] = MFMA16(ldsA(smem, 24576, h * 16 + c, g * 8, 64), tb0, vz);
        vacc[h] = MFMA16(ldsA(smem, 24576, h * 16 + c, 32 + g * 8, 64), tb1, vacc[h]);
      }
      const float bt = (tt == 0) ? b0 : (tt == 1) ? b1 : (tt == 2) ? b2 : b3;
#pragma unroll
      for (int h = 0; h < 4; ++h) {
        float d = qacc[h][0] * kacc[h][0] + qacc[h][1] * kacc[h][1] +
                  qacc[h][2] * kacc[h][2] + qacc[h][3] * kacc[h][3];
        d += __shfl_xor(d, 16);
        d += __shfl_xor(d, 32);
        float e = __expf(d + bt);
        ssum[h] += e;
        oacc[h] += e * vacc[h];
      }
    }
#pragma unroll
    for (int h = 0; h < 4; ++h) {
      float inv = 1.0f / ssum[h];
      f32x4 o = oacc[h] * inv;
      u32x2 w;
      w.x = cvtpk(o[0], o[1]);
      w.y = cvtpk(o[2], o[3]);
      int off = (c * 128 + h * 32 + g * 8) ^ ((c & 7) << 4);
      *(u32x2*)(Olds + off) = w;
    }
    asm volatile("s_waitcnt lgkmcnt(0)" ::: "memory");
    f32x4 outacc[8] = {vz, vz, vz, vz, vz, vz, vz, vz};
#pragma unroll
    for (int s = 0; s < 2; ++s) {
      int off = (c * 128 + s * 64 + g * 16) ^ ((c & 7) << 4);
      bf16x8 ob = __builtin_bit_cast(bf16x8, *(const u32x4*)(Olds + off));
#pragma unroll
      for (int m = 0; m < 8; ++m)
        outacc[m] = MFMA16(ldsA(smem, 32768, m * 16 + c, s * 32 + g * 8, 64), ob, outacc[m]);
    }
    float* op = out_ + (size_t)p * 128;
    const float4* bop = (const float4*)bo_;
#pragma unroll
    for (int m = 0; m < 8; ++m) {
      float4 bv = bop[m * 4 + g];
      float4 st;
      st.x = outacc[m][0] + bv.x;
      st.y = outacc[m][1] + bv.y;
      st.z = outacc[m][2] + bv.z;
      st.w = outacc[m][3] + bv.w;
      *(float4*)(op + m * 16 + g * 4) = st;
    }
    asm volatile("" ::: "memory");
  }
}

extern "C" void kernel_launch(void* const* d_in, const int* in_sizes, int n_in,
                              void* d_out, int out_size, void* d_ws, size_t ws_size,
                              hipStream_t stream) {
  const float* t = (const float*)d_in[0];
  const float* z = (const float*)d_in[1];
  const float* mk = (const float*)d_in[2];
  const float* wq = (const float*)d_in[3];
  const float* wk = (const float*)d_in[4];
  const float* wv = (const float*)d_in[5];
  const float* wo = (const float*)d_in[6];
  const float* bo = (const float*)d_in[7];
  float* out = (float*)d_out;
  (void)in_sizes; (void)n_in; (void)out_size;

  const size_t qbytes = (size_t)9216 * 4 * 64 * 8;  // Q fragments as u32x2
  if (ws_size >= qbytes) {
    u32x2* qws = (u32x2*)d_ws;
    hipLaunchKernelGGL(q_kernel, dim3(1152), dim3(256), 16384, stream, z, wq, qws);
    hipLaunchKernelGGL(tpa_b_kernel, dim3(1024), dim3(256), 40960, stream,
                       t, qws, mk, wk, wv, wo, bo, out);
  } else {
    hipLaunchKernelGGL(tpa_fused, dim3(512), dim3(256), 57344, stream,
                       t, z, mk, wq, wk, wv, wo, bo, out);
  }
}

// Round 7
// 91.133 us; speedup vs baseline: 1.9110x; 1.2946x over previous
//
#include <hip/hip_runtime.h>

// TemplatePointwiseAttention on MI355X (gfx950).
// T=4 templates, R=384, d_t=64, d_z=128, H=4 heads, D=16.
// R7: pass B rewritten as a block-cooperative 2-phase pipeline:
//   512-thr block, 64 px/step, 9 steps (grid 256, exact).
//   loop: pack+ds_write t(step) [staged in regs last iter] -> issue t(step+1)
//         -> barrier(lgkm only) -> QK/PV from LDS -> O to LDS -> barrier
//         -> OUT GEMM + store.
//   Raw s_barrier + lgkmcnt(0) keeps ~64KB of global loads in flight per CU
//   across barriers (the __syncthreads vmcnt(0) drain would serialize).
//   R5/R6 showed per-wave MLP (~2.7KB/CU in flight) pins BW at 1.58 TB/s.

typedef __bf16 bf16x8 __attribute__((ext_vector_type(8)));
typedef float f32x4 __attribute__((ext_vector_type(4)));
typedef unsigned int u32x4 __attribute__((ext_vector_type(4)));
typedef unsigned int u32x2 __attribute__((ext_vector_type(2)));

#define MFMA16(A, B, C) __builtin_amdgcn_mfma_f32_16x16x32_bf16((A), (B), (C), 0, 0, 0)

// lgkm-only barrier: LDS visibility without draining vmcnt (keeps global
// staging loads in flight). sched_barrier + "memory" fence both sides (rule 18).
#define BARRIER_LGKM()                                      \
  do {                                                      \
    asm volatile("s_waitcnt lgkmcnt(0)" ::: "memory");      \
    __builtin_amdgcn_sched_barrier(0);                      \
    __builtin_amdgcn_s_barrier();                           \
    __builtin_amdgcn_sched_barrier(0);                      \
    asm volatile("" ::: "memory");                          \
  } while (0)

// hardware packed f32->bf16 (RNE): lo -> low16, hi -> high16
__device__ __forceinline__ unsigned int cvtpk(float lo, float hi) {
  unsigned int r;
  asm("v_cvt_pk_bf16_f32 %0, %1, %2" : "=v"(r) : "v"(lo), "v"(hi));
  return r;
}

__device__ __forceinline__ bf16x8 pack8(float4 a, float4 b) {
  u32x4 u;
  u.x = cvtpk(a.x, a.y);
  u.y = cvtpk(a.z, a.w);
  u.z = cvtpk(b.x, b.y);
  u.w = cvtpk(b.z, b.w);
  return __builtin_bit_cast(bf16x8, u);
}

// A-fragment from XOR-swizzled LDS image: row-major [M][K] bf16,
// swizzle byte ^= (row&7)<<4
__device__ __forceinline__ bf16x8 ldsA(const char* smem, int baseByte, int row,
                                       int colElem, int strideElem) {
  int off = baseByte + (((row * strideElem + colElem) * 2) ^ ((row & 7) << 4));
  return __builtin_bit_cast(bf16x8, *(const u32x4*)(smem + off));
}

// t-tile B-fragment from TBUF [4tt][64px][64d] bf16, swizzle byte ^= (px&7)<<4
__device__ __forceinline__ bf16x8 ldsT(const char* TB, int tt, int px, int kElem) {
  int off = ((((tt * 64 + px) << 7) + (kElem << 1))) ^ ((px & 7) << 4);
  return __builtin_bit_cast(bf16x8, *(const u32x4*)(TB + off));
}

__device__ __forceinline__ void stage_w(char* smem, int off, float v, int r, int j) {
  unsigned int u = __float_as_uint(v);
  *(unsigned short*)(smem + off + ((j * 2) ^ ((r & 7) << 4))) =
      (unsigned short)((u + 0x7fffu + ((u >> 16) & 1u)) >> 16);
}

// ---------------- Pass A: Q^T = (wq^T * 0.25) * z^T, bf16 out ----------------
// (unchanged from R6 — runs at ~5-6 TB/s)
__global__ __launch_bounds__(256, 2)
void q_kernel(const float* __restrict__ z_, const float* __restrict__ wq_,
              u32x2* __restrict__ q_) {
  extern __shared__ char smem[];
  for (int i = threadIdx.x; i < 8192; i += 256) {
    int r = i >> 7, cc = i & 127;
    stage_w(smem, 0, wq_[cc * 64 + r] * 0.25f, r, i);
  }
  __syncthreads();
  const int lane = threadIdx.x & 63;
  const int wid = threadIdx.x >> 6;
  const int c = lane & 15, g = lane >> 4;
  const f32x4 vz = {0.f, 0.f, 0.f, 0.f};
  for (int tile = blockIdx.x * 4 + wid; tile < 9216; tile += 4608) {
    const int p = tile * 16 + c;
    const float4* zp = (const float4*)(z_ + (size_t)p * 128 + g * 8);
    float4 zraw[8];
#pragma unroll
    for (int s = 0; s < 4; ++s) {
      zraw[2 * s] = zp[s * 8];
      zraw[2 * s + 1] = zp[s * 8 + 1];
    }
    f32x4 qacc[4] = {vz, vz, vz, vz};
#pragma unroll
    for (int s = 0; s < 4; ++s) {
      bf16x8 zb = pack8(zraw[2 * s], zraw[2 * s + 1]);
#pragma unroll
      for (int h = 0; h < 4; ++h)
        qacc[h] = MFMA16(ldsA(smem, 0, h * 16 + c, s * 32 + g * 8, 128), zb, qacc[h]);
    }
#pragma unroll
    for (int h = 0; h < 4; ++h) {
      u32x2 w;
      w.x = cvtpk(qacc[h][0], qacc[h][1]);
      w.y = cvtpk(qacc[h][2], qacc[h][3]);
      q_[(size_t)(tile * 4 + h) * 64 + lane] = w;
    }
  }
}

// ---------------- Pass B: pipelined attention + output projection -----------
// LDS: [0,8192) wk^T [64][64] | [8192,16384) wv^T | [16384,32768) wo^T [128][64]
//      [32768,65536) TBUF [4tt][64px][64d] bf16 (px-swizzled)
//      [65536,73728) Olds 4 x [16px][64] bf16 (c-swizzled)
__global__ __launch_bounds__(512, 1)
void tpa_b_kernel(const float* __restrict__ t_, const u32x2* __restrict__ q_,
                  const float* __restrict__ mask_,
                  const float* __restrict__ wk_, const float* __restrict__ wv_,
                  const float* __restrict__ wo_, const float* __restrict__ bo_,
                  float* __restrict__ out_) {
  extern __shared__ char smem[];
  char* TB = smem + 32768;

  for (int i = threadIdx.x; i < 16384; i += 512) {
    if (i < 4096) {
      int r = i >> 6, cc = i & 63;
      stage_w(smem, 0, wk_[cc * 64 + r], r, i);
    } else if (i < 8192) {
      int j = i - 4096, r = j >> 6, cc = j & 63;
      stage_w(smem, 8192, wv_[cc * 64 + r], r, j);
    } else {
      int j = i - 8192, r = j >> 6, cc = j & 63;
      stage_w(smem, 16384, wo_[cc * 128 + r], r, j);
    }
  }
  __syncthreads();

  const int tid = threadIdx.x;
  const int lane = tid & 63, wid = tid >> 6;
  const int c = lane & 15, g = lane >> 4;
  const int q4 = wid & 3;   // px-quarter (16 px)
  const int hp = wid >> 2;  // head-pair (QK/PV) and feat-half (OUT)
  const int px = q4 * 16 + c;
  char* Olds = smem + 65536 + q4 * 2048;

  const float b0 = mask_[0] > 0.f ? 0.f : -1e9f;
  const float b1 = mask_[1] > 0.f ? 0.f : -1e9f;
  const float b2 = mask_[2] > 0.f ? 0.f : -1e9f;
  const float b3 = mask_[3] > 0.f ? 0.f : -1e9f;

  // bo for this wave's (feat-half, g) — loop-invariant
  float4 bov[4];
#pragma unroll
  for (int m = 0; m < 4; ++m) bov[m] = *(const float4*)(bo_ + hp * 64 + m * 16 + g * 4);

  // staging assignment: thread covers 8 consecutive floats of each tt-region
  const int spx = tid >> 3;    // 0..63 pixel-in-step
  const int schunk = tid & 7;  // 8-float chunk
  const f32x4 vz = {0.f, 0.f, 0.f, 0.f};

  float4 ra[8];
  u32x2 qcur[2], qnext[2];

  auto issue_step = [&](int step, u32x2* qw) {
    const float* base = t_ + ((size_t)step * 64 + spx) * 64 + schunk * 8;
#pragma unroll
    for (int tt = 0; tt < 4; ++tt) {
      const float* p4 = base + (size_t)tt * 9437184;  // tt * R*R*64
      ra[tt * 2] = *(const float4*)(p4);
      ra[tt * 2 + 1] = *(const float4*)(p4 + 4);
    }
    const int stile = step * 4 + q4;
#pragma unroll
    for (int h = 0; h < 2; ++h)
      qw[h] = q_[(size_t)(stile * 4 + hp * 2 + h) * 64 + lane];
  };

  // 2304 steps = 256 blocks x 9, exact
  issue_step(blockIdx.x, qcur);

  for (int k = 0; k < 9; ++k) {
    const int step = blockIdx.x + k * 256;

    // ---- pack staged regs -> TBUF (bf16, swizzled; consumes ra/vmcnt) ----
#pragma unroll
    for (int tt = 0; tt < 4; ++tt) {
      bf16x8 w = pack8(ra[tt * 2], ra[tt * 2 + 1]);
      int off = ((((tt * 64 + spx) << 7) + (schunk << 4))) ^ ((spx & 7) << 4);
      *(u32x4*)(TB + off) = __builtin_bit_cast(u32x4, w);
    }
    if (k < 8) issue_step(step + 256, qnext);  // next step's loads in flight
    BARRIER_LGKM();  // TBUF ready; staging loads NOT drained

    // ---- QK/PV for this wave's 16 px x 2 heads ----
    f32x4 qacc[2];
#pragma unroll
    for (int h = 0; h < 2; ++h) {
      qacc[h][0] = __uint_as_float(qcur[h].x << 16);
      qacc[h][1] = __uint_as_float(qcur[h].x & 0xffff0000u);
      qacc[h][2] = __uint_as_float(qcur[h].y << 16);
      qacc[h][3] = __uint_as_float(qcur[h].y & 0xffff0000u);
    }
    f32x4 oacc[2] = {vz, vz};
    float ssum[2] = {0.f, 0.f};
#pragma unroll
    for (int tt = 0; tt < 4; ++tt) {
      bf16x8 tb0 = ldsT(TB, tt, px, g * 8);
      bf16x8 tb1 = ldsT(TB, tt, px, 32 + g * 8);
      const float bt = (tt == 0) ? b0 : (tt == 1) ? b1 : (tt == 2) ? b2 : b3;
#pragma unroll
      for (int h = 0; h < 2; ++h) {
        const int row = (hp * 2 + h) * 16 + c;
        f32x4 kacc = MFMA16(ldsA(smem, 0, row, g * 8, 64), tb0, vz);
        kacc = MFMA16(ldsA(smem, 0, row, 32 + g * 8, 64), tb1, kacc);
        f32x4 vacc = MFMA16(ldsA(smem, 8192, row, g * 8, 64), tb0, vz);
        vacc = MFMA16(ldsA(smem, 8192, row, 32 + g * 8, 64), tb1, vacc);
        float d = qacc[h][0] * kacc[0] + qacc[h][1] * kacc[1] +
                  qacc[h][2] * kacc[2] + qacc[h][3] * kacc[3];
        d += __shfl_xor(d, 16);
        d += __shfl_xor(d, 32);  // full 16-d dot broadcast to all g-groups
        float e = __expf(d + bt);
        ssum[h] += e;
        oacc[h] += e * vacc;
      }
    }

    // ---- normalize, O -> Olds (bf16, swizzled; cross-wave exchange) ----
#pragma unroll
    for (int h = 0; h < 2; ++h) {
      float inv = 1.0f / ssum[h];
      f32x4 o = oacc[h] * inv;
      u32x2 w;
      w.x = cvtpk(o[0], o[1]);
      w.y = cvtpk(o[2], o[3]);
      int off = (c * 128 + (hp * 2 + h) * 32 + g * 8) ^ ((c & 7) << 4);
      *(u32x2*)(Olds + off) = w;
    }
    BARRIER_LGKM();  // Olds ready

    // ---- OUT^T = wo^T * O^T: this wave does (px-quarter q4, feat-half hp) --
    f32x4 outacc[4] = {vz, vz, vz, vz};
#pragma unroll
    for (int s = 0; s < 2; ++s) {
      int off = (c * 128 + s * 64 + g * 16) ^ ((c & 7) << 4);
      bf16x8 ob = __builtin_bit_cast(bf16x8, *(const u32x4*)(Olds + off));
#pragma unroll
      for (int m = 0; m < 4; ++m)
        outacc[m] = MFMA16(ldsA(smem, 16384, hp * 64 + m * 16 + c, s * 32 + g * 8, 64),
                           ob, outacc[m]);
    }
    float* op = out_ + ((size_t)step * 64 + px) * 128 + hp * 64;
#pragma unroll
    for (int m = 0; m < 4; ++m) {
      float4 st;
      st.x = outacc[m][0] + bov[m].x;
      st.y = outacc[m][1] + bov[m].y;
      st.z = outacc[m][2] + bov[m].z;
      st.w = outacc[m][3] + bov[m].w;
      *(float4*)(op + m * 16 + g * 4) = st;
    }
    if (k < 8) {
      qcur[0] = qnext[0];
      qcur[1] = qnext[1];
    }
    // next iter's TBUF ds_write is safe: all TBUF reads finished before the
    // Olds barrier above; next BARRIER_LGKM orders Olds reuse.
  }
}

// ---------------- Fallback: single-pass (R0-shape, verified), ws too small --
__global__ __launch_bounds__(256, 2)
void tpa_fused(const float* __restrict__ t_, const float* __restrict__ z_,
               const float* __restrict__ mask_,
               const float* __restrict__ wq_, const float* __restrict__ wk_,
               const float* __restrict__ wv_, const float* __restrict__ wo_,
               const float* __restrict__ bo_, float* __restrict__ out_) {
  extern __shared__ char smem[];
  for (int i = threadIdx.x; i < 24576; i += 256) {
    if (i < 8192) {
      int r = i >> 7;
      stage_w(smem, 0, wq_[(i & 127) * 64 + r] * 0.25f, r, i);
    } else if (i < 12288) {
      int j = i - 8192, r = j >> 6;
      stage_w(smem, 16384, wk_[(j & 63) * 64 + r], r, j);
    } else if (i < 16384) {
      int j = i - 12288, r = j >> 6;
      stage_w(smem, 24576, wv_[(j & 63) * 64 + r], r, j);
    } else {
      int j = i - 16384, r = j >> 6;
      stage_w(smem, 32768, wo_[(j & 63) * 128 + r], r, j);
    }
  }
  __syncthreads();
  const int lane = threadIdx.x & 63;
  const int wid = threadIdx.x >> 6;
  const int c = lane & 15, g = lane >> 4;
  const float b0 = mask_[0] > 0.f ? 0.f : -1e9f;
  const float b1 = mask_[1] > 0.f ? 0.f : -1e9f;
  const float b2 = mask_[2] > 0.f ? 0.f : -1e9f;
  const float b3 = mask_[3] > 0.f ? 0.f : -1e9f;
  char* Olds = smem + 49152 + wid * 2048;
  const f32x4 vz = {0.f, 0.f, 0.f, 0.f};
  for (int tile = blockIdx.x * 4 + wid; tile < 9216; tile += 2048) {
    const int p = tile * 16 + c;
    const float4* zp = (const float4*)(z_ + (size_t)p * 128 + g * 8);
    const float* tp = t_ + (size_t)p * 64 + g * 8;
    f32x4 qacc[4] = {vz, vz, vz, vz};
#pragma unroll
    for (int s = 0; s < 4; ++s) {
      bf16x8 zb = pack8(zp[s * 8], zp[s * 8 + 1]);
#pragma unroll
      for (int h = 0; h < 4; ++h)
        qacc[h] = MFMA16(ldsA(smem, 0, h * 16 + c, s * 32 + g * 8, 128), zb, qacc[h]);
    }
    f32x4 oacc[4] = {vz, vz, vz, vz};
    float ssum[4] = {0.f, 0.f, 0.f, 0.f};
#pragma unroll
    for (int tt = 0; tt < 4; ++tt) {
      const float* tq = tp + (size_t)tt * 9437184;
      bf16x8 tb0 = pack8(*(const float4*)(tq), *(const float4*)(tq + 4));
      bf16x8 tb1 = pack8(*(const float4*)(tq + 32), *(const float4*)(tq + 36));
      f32x4 kacc[4], vacc[4];
#pragma unroll
      for (int h = 0; h < 4; ++h) {
        kacc[h] = MFMA16(ldsA(smem, 16384, h * 16 + c, g * 8, 64), tb0, vz);
        kacc[h] = MFMA16(ldsA(smem, 16384, h * 16 + c, 32 + g * 8, 64), tb1, kacc[h]);
        vacc[h] = MFMA16(ldsA(smem, 24576, h * 16 + c, g * 8, 64), tb0, vz);
        vacc[h] = MFMA16(ldsA(smem, 24576, h * 16 + c, 32 + g * 8, 64), tb1, vacc[h]);
      }
      const float bt = (tt == 0) ? b0 : (tt == 1) ? b1 : (tt == 2) ? b2 : b3;
#pragma unroll
      for (int h = 0; h < 4; ++h) {
        float d = qacc[h][0] * kacc[h][0] + qacc[h][1] * kacc[h][1] +
                  qacc[h][2] * kacc[h][2] + qacc[h][3] * kacc[h][3];
        d += __shfl_xor(d, 16);
        d += __shfl_xor(d, 32);
        float e = __expf(d + bt);
        ssum[h] += e;
        oacc[h] += e * vacc[h];
      }
    }
#pragma unroll
    for (int h = 0; h < 4; ++h) {
      float inv = 1.0f / ssum[h];
      f32x4 o = oacc[h] * inv;
      u32x2 w;
      w.x = cvtpk(o[0], o[1]);
      w.y = cvtpk(o[2], o[3]);
      int off = (c * 128 + h * 32 + g * 8) ^ ((c & 7) << 4);
      *(u32x2*)(Olds + off) = w;
    }
    asm volatile("s_waitcnt lgkmcnt(0)" ::: "memory");
    f32x4 outacc[8] = {vz, vz, vz, vz, vz, vz, vz, vz};
#pragma unroll
    for (int s = 0; s < 2; ++s) {
      int off = (c * 128 + s * 64 + g * 16) ^ ((c & 7) << 4);
      bf16x8 ob = __builtin_bit_cast(bf16x8, *(const u32x4*)(Olds + off));
#pragma unroll
      for (int m = 0; m < 8; ++m)
        outacc[m] = MFMA16(ldsA(smem, 32768, m * 16 + c, s * 32 + g * 8, 64), ob, outacc[m]);
    }
    float* op = out_ + (size_t)p * 128;
    const float4* bop = (const float4*)bo_;
#pragma unroll
    for (int m = 0; m < 8; ++m) {
      float4 bv = bop[m * 4 + g];
      float4 st;
      st.x = outacc[m][0] + bv.x;
      st.y = outacc[m][1] + bv.y;
      st.z = outacc[m][2] + bv.z;
      st.w = outacc[m][3] + bv.w;
      *(float4*)(op + m * 16 + g * 4) = st;
    }
    asm volatile("" ::: "memory");
  }
}

extern "C" void kernel_launch(void* const* d_in, const int* in_sizes, int n_in,
                              void* d_out, int out_size, void* d_ws, size_t ws_size,
                              hipStream_t stream) {
  const float* t = (const float*)d_in[0];
  const float* z = (const float*)d_in[1];
  const float* mk = (const float*)d_in[2];
  const float* wq = (const float*)d_in[3];
  const float* wk = (const float*)d_in[4];
  const float* wv = (const float*)d_in[5];
  const float* wo = (const float*)d_in[6];
  const float* bo = (const float*)d_in[7];
  float* out = (float*)d_out;
  (void)in_sizes; (void)n_in; (void)out_size;

  const size_t qbytes = (size_t)9216 * 4 * 64 * 8;  // Q fragments as u32x2
  if (ws_size >= qbytes) {
    u32x2* qws = (u32x2*)d_ws;
    hipLaunchKernelGGL(q_kernel, dim3(1152), dim3(256), 16384, stream, z, wq, qws);
    hipLaunchKernelGGL(tpa_b_kernel, dim3(256), dim3(512), 73728, stream,
                       t, qws, mk, wk, wv, wo, bo, out);
  } else {
    hipLaunchKernelGGL(tpa_fused, dim3(512), dim3(256), 57344, stream,
                       t, z, mk, wq, wk, wv, wo, bo, out);
  }
}